// Round 8
// baseline (137.513 us; speedup 1.0000x reference)
//
#include <hip/hip_runtime.h>
#include <math.h>

// VectorQuantizer on MI355X — R18: fence-free single-kernel fusion.
// R17 post-mortem: occupancy 26->60% at constant work = no change -> vq_main
// (~40 µs) is NOT TLP-starved; and ~25 µs of budget sits in final+graph gaps
// (unattributable: vq_main hides under the 43.5 µs fill cutoff).
// R12's fusion failed via __threadfence() = buffer_wbl2 per block (drains the
// XCD L2's ~4 MB of dirty `out` stream, 512x). R18 publishes ONLY the
// cross-block data coherently: agent-scope atomic stores for pcounts/ssep
// (write-through to coherent point), per-block RELEASE flag (vmcnt(0) only,
// no wbl2), magic flag value so poisoned ws needs no init memset. Block 0
// spins on flags, pulls 1 MB via agent-scope loads (bypass stale local L2),
// writes loss/perplexity. Graph = ONE kernel, zero memsets.
// Compute body bit-identical to R17 (split-K 32 KB wh, 512x256 tokens).
// Lessons kept: no nontemporal out (R12 +43MB), plain cached epilogue,
// no threadfence/wbl2 (R12/R13 ~40µs).
// ws: [0,1MB) pcounts u32[512][512] | [1MB,+4K) ssep u64[512] | [+2K) flags

#define NTOK 131072
#define KCODES 512
#define HW 4096
#define CHW 262144
#define NELEM 8388608
#define FLAG_MAGIC 0x5AFE0512u

typedef __attribute__((ext_vector_type(8))) short short8;
typedef __attribute__((ext_vector_type(4))) float f32x4;

static __device__ __forceinline__ unsigned short f2bf(float f) {
    unsigned u = __float_as_uint(f);
    unsigned r = u + 0x7FFFu + ((u >> 16) & 1u);  // RNE
    return (unsigned short)(r >> 16);
}

__global__ __launch_bounds__(512, 8) void vq_main(const float* __restrict__ in,
                                                  const float* __restrict__ w,
                                                  float* __restrict__ out,
                                                  unsigned* __restrict__ pcounts,
                                                  unsigned long long* __restrict__ ssep,
                                                  unsigned* __restrict__ flags,
                                                  float* __restrict__ counts,
                                                  double* __restrict__ sse_acc,
                                                  const int amode) {
    __shared__ __align__(16) unsigned short wh[256 * 64];  // 32768 B half-codebook
    __shared__ float wsqp[KCODES];              // 2048 B: 1.25 + ||w_k||^2
    __shared__ int idxbuf[256];                 // 1024 B
    __shared__ int hist[KCODES];                // 2048 B block histogram
    __shared__ double sred[8];                  // per-wave sse partials

    const int tid = threadIdx.x;
    const int lane = tid & 63, wv = tid >> 6;   // wv in [0,8)
    const int col = lane & 15, quad = lane >> 4;
    const int ntok0 = blockIdx.x * 256;         // 512 blocks x 256 tokens

    wsqp[tid] = 1.25f;
    hist[tid] = 0;
    __syncthreads();  // B1: wsqp/hist init before use

    // ---- phase 1: pass-0 W staging (codes 0..255) interleaved with all X ----
    const float* gbase = in + (ntok0 >> 12) * CHW + (ntok0 & 4095) + wv * 32 + col;
    short8 ah[2][2];
    float xsq = 0.f;
#pragma unroll
    for (int it = 0; it < 8; ++it) {
        const int sub = it >> 2, c = (it >> 1) & 1, j0 = (it & 1) * 4;
        const float* gp = gbase + sub * 16 + (c * 32 + quad * 8 + j0) * HW;
        const float x0 = gp[0 * HW], x1 = gp[1 * HW], x2 = gp[2 * HW], x3 = gp[3 * HW];

        if (it < 4) {
            const int g = it * 512 + tid;  // [0,2048): 256 codes x 8 chunks
            const int cc = g & 15, qd = (g >> 4) & 3, ch = (g >> 6) & 1, tt = g >> 7;
            const int code = tt * 16 + cc;
            const float4* src = (const float4*)(w + code * 64 + ch * 32 + qd * 8);
            const float4 v0 = src[0], v1 = src[1];
            short8 hv;
            hv[0] = (short)f2bf(v0.x); hv[1] = (short)f2bf(v0.y);
            hv[2] = (short)f2bf(v0.z); hv[3] = (short)f2bf(v0.w);
            hv[4] = (short)f2bf(v1.x); hv[5] = (short)f2bf(v1.y);
            hv[6] = (short)f2bf(v1.z); hv[7] = (short)f2bf(v1.w);
            *(short8*)(wh + g * 8) = hv;
            float ws2 = v0.x * v0.x;
            ws2 = fmaf(v0.y, v0.y, ws2); ws2 = fmaf(v0.z, v0.z, ws2);
            ws2 = fmaf(v0.w, v0.w, ws2); ws2 = fmaf(v1.x, v1.x, ws2);
            ws2 = fmaf(v1.y, v1.y, ws2); ws2 = fmaf(v1.z, v1.z, ws2);
            ws2 = fmaf(v1.w, v1.w, ws2);
            atomicAdd(&wsqp[code], ws2);  // LDS atomic
        }

        ah[sub][c][j0 + 0] = (short)f2bf(-2.0f * x0);
        ah[sub][c][j0 + 1] = (short)f2bf(-2.0f * x1);
        ah[sub][c][j0 + 2] = (short)f2bf(-2.0f * x2);
        ah[sub][c][j0 + 3] = (short)f2bf(-2.0f * x3);
        xsq = fmaf(x0, x0, xsq); xsq = fmaf(x1, x1, xsq);
        xsq = fmaf(x2, x2, xsq); xsq = fmaf(x3, x3, xsq);
    }
    __syncthreads();  // B2: pass-0 wh + wsqp[0:256] complete

    unsigned runkey[2][4];
#pragma unroll
    for (int sub = 0; sub < 2; ++sub)
#pragma unroll
        for (int r = 0; r < 4; ++r) runkey[sub][r] = 0xFFFFFFFFu;

    // ---- scan pass 0: codes 0..255 ----
#pragma unroll 1
    for (int t = 0; t < 16; ++t) {
        const unsigned short* ph = wh + t * 1024 + quad * 128 + col * 8;
        const short8 b0 = *(const short8*)ph;
        const short8 b1 = *(const short8*)(ph + 512);
        const int code = t * 16 + col;
        const float seed = wsqp[code];
#pragma unroll
        for (int sub = 0; sub < 2; ++sub) {
            f32x4 acc = {seed, seed, seed, seed};
            acc = __builtin_amdgcn_mfma_f32_16x16x32_bf16(ah[sub][0], b0, acc, 0, 0, 0);
            acc = __builtin_amdgcn_mfma_f32_16x16x32_bf16(ah[sub][1], b1, acc, 0, 0, 0);
#pragma unroll
            for (int r = 0; r < 4; ++r) {
                const unsigned key = (__float_as_uint(acc[r]) << 9) | code;
                runkey[sub][r] = key < runkey[sub][r] ? key : runkey[sub][r];
            }
        }
    }
    __syncthreads();  // B3: all waves done reading pass-0 wh

    // ---- pass-1 staging (codes 256..511) ----
#pragma unroll
    for (int it = 0; it < 4; ++it) {
        const int g = it * 512 + tid;
        const int cc = g & 15, qd = (g >> 4) & 3, ch = (g >> 6) & 1, tt = g >> 7;
        const int code = 256 + tt * 16 + cc;
        const float4* src = (const float4*)(w + code * 64 + ch * 32 + qd * 8);
        const float4 v0 = src[0], v1 = src[1];
        short8 hv;
        hv[0] = (short)f2bf(v0.x); hv[1] = (short)f2bf(v0.y);
        hv[2] = (short)f2bf(v0.z); hv[3] = (short)f2bf(v0.w);
        hv[4] = (short)f2bf(v1.x); hv[5] = (short)f2bf(v1.y);
        hv[6] = (short)f2bf(v1.z); hv[7] = (short)f2bf(v1.w);
        *(short8*)(wh + g * 8) = hv;
        float ws2 = v0.x * v0.x;
        ws2 = fmaf(v0.y, v0.y, ws2); ws2 = fmaf(v0.z, v0.z, ws2);
        ws2 = fmaf(v0.w, v0.w, ws2); ws2 = fmaf(v1.x, v1.x, ws2);
        ws2 = fmaf(v1.y, v1.y, ws2); ws2 = fmaf(v1.z, v1.z, ws2);
        ws2 = fmaf(v1.w, v1.w, ws2);
        atomicAdd(&wsqp[code], ws2);
    }
    __syncthreads();  // B4: pass-1 wh + wsqp[256:512] complete

    // ---- scan pass 1: codes 256..511 ----
#pragma unroll 1
    for (int t = 0; t < 16; ++t) {
        const unsigned short* ph = wh + t * 1024 + quad * 128 + col * 8;
        const short8 b0 = *(const short8*)ph;
        const short8 b1 = *(const short8*)(ph + 512);
        const int code = 256 + t * 16 + col;
        const float seed = wsqp[code];
#pragma unroll
        for (int sub = 0; sub < 2; ++sub) {
            f32x4 acc = {seed, seed, seed, seed};
            acc = __builtin_amdgcn_mfma_f32_16x16x32_bf16(ah[sub][0], b0, acc, 0, 0, 0);
            acc = __builtin_amdgcn_mfma_f32_16x16x32_bf16(ah[sub][1], b1, acc, 0, 0, 0);
#pragma unroll
            for (int r = 0; r < 4; ++r) {
                const unsigned key = (__float_as_uint(acc[r]) << 9) | code;
                runkey[sub][r] = key < runkey[sub][r] ? key : runkey[sub][r];
            }
        }
    }

    // ---- cross-lane argmin over the 16 code-cols ----
#pragma unroll
    for (int s = 1; s < 16; s <<= 1)
#pragma unroll
        for (int sub = 0; sub < 2; ++sub)
#pragma unroll
            for (int r = 0; r < 4; ++r) {
                const unsigned o = __shfl_xor(runkey[sub][r], s, 64);
                runkey[sub][r] = o < runkey[sub][r] ? o : runkey[sub][r];
            }

    // d_best (exact from key) + publish indices (wave-local consumers only)
    float dsum = 0.f;
    if (col == 0) {
#pragma unroll
        for (int sub = 0; sub < 2; ++sub)
#pragma unroll
            for (int r = 0; r < 4; ++r) {
                const unsigned key = runkey[sub][r];
                idxbuf[wv * 32 + sub * 16 + quad * 4 + r] = (int)(key & 511u);
                dsum += __uint_as_float((key >> 9) | 0x3F800000u) - 1.25f;
            }
    }
    float contrib = xsq + dsum;
#pragma unroll
    for (int off = 32; off > 0; off >>= 1) contrib += __shfl_down(contrib, off, 64);
    if (lane == 0) sred[wv] = (double)contrib;

    // per-wave histogram over wave-local idxbuf
    if (lane < 32) atomicAdd(&hist[idxbuf[wv * 32 + lane]], 1);

    // ---- epilogue: write w rows only (L2-hot); 4 lanes/token, 2 passes ----
#pragma unroll
    for (int p = 0; p < 2; ++p) {
        const int tl = p * 16 + (lane >> 2), q = lane & 3;
        const int n = ntok0 + wv * 32 + tl;
        const int bidx = idxbuf[wv * 32 + tl];
        const float4* wr = (const float4*)(w + bidx * 64 + q * 16);
        float4* op = (float4*)(out + n * 64 + q * 16);
#pragma unroll
        for (int i = 0; i < 4; ++i) op[i] = wr[i];
    }
    __syncthreads();  // B5: hist + sred complete

    if (!amode) {
        // publish partials at AGENT scope (write-through to coherent point;
        // no wbl2, no L2 drain of the streaming out-data — R12's mistake)
        __hip_atomic_store(&pcounts[(blockIdx.x << 9) + tid], (unsigned)hist[tid],
                           __ATOMIC_RELAXED, __HIP_MEMORY_SCOPE_AGENT);
        if (tid == 0) {
            double s = sred[0];
#pragma unroll
            for (int i = 1; i < 8; ++i) s += sred[i];
            __hip_atomic_store(&ssep[blockIdx.x],
                               (unsigned long long)__double_as_longlong(s),
                               __ATOMIC_RELAXED, __HIP_MEMORY_SCOPE_AGENT);
        }
        __syncthreads();  // all waves' stores drained (vmcnt 0 before barrier)
        if (tid == 0)
            __hip_atomic_store(&flags[blockIdx.x], FLAG_MAGIC,
                               __ATOMIC_RELEASE, __HIP_MEMORY_SCOPE_AGENT);

        if (blockIdx.x == 0) {  // reducer: spin on flags, then pull partials
            for (;;) {
                const unsigned f = __hip_atomic_load(&flags[tid], __ATOMIC_RELAXED,
                                                     __HIP_MEMORY_SCOPE_AGENT);
                if (__syncthreads_and(f == FLAG_MAGIC)) break;
                __builtin_amdgcn_s_sleep(16);
            }
            // column-sum: thread tid sums pcounts[b][tid] over 512 rows.
            // agent-scope loads bypass this XCD's (possibly poison-stale) L2.
            unsigned c0 = 0, c1 = 0, c2 = 0, c3 = 0;
            const unsigned* pc = pcounts + tid;
#pragma unroll 2
            for (int b = 0; b < 512; b += 16) {
                unsigned v[16];
#pragma unroll
                for (int j = 0; j < 16; ++j)
                    v[j] = __hip_atomic_load(pc + ((b + j) << 9), __ATOMIC_RELAXED,
                                             __HIP_MEMORY_SCOPE_AGENT);
#pragma unroll
                for (int j = 0; j < 16; j += 4) {
                    c0 += v[j]; c1 += v[j + 1]; c2 += v[j + 2]; c3 += v[j + 3];
                }
            }
            const float cnt = (float)(c0 + c1 + c2 + c3);  // integer-exact
            double* const dred = (double*)wh;   // wh dead past scan: scratch
            double* const dsred = dred + KCODES;
            const double p = (double)cnt / (double)NTOK;
            dred[tid] = p * log(p + 1e-10);
            dsred[tid] = __longlong_as_double(
                (long long)__hip_atomic_load(&ssep[tid], __ATOMIC_RELAXED,
                                             __HIP_MEMORY_SCOPE_AGENT));
            __syncthreads();
#pragma unroll
            for (int st = 256; st > 0; st >>= 1) {
                if (tid < st) {
                    dred[tid] += dred[tid + st];
                    dsred[tid] += dsred[tid + st];
                }
                __syncthreads();
            }
            if (tid == 0) {
                out[NELEM] = (float)((dsred[0] / (double)NELEM) * 1.25);
                out[NELEM + 1] = (float)exp(-dred[0]);
            }
        }
    } else {  // fallback: ws too small for partials
        const int h = hist[tid];
        if (h) atomicAdd(&counts[tid], (float)h);
        if (tid == 0) {
            double s = sred[0];
#pragma unroll
            for (int i = 1; i < 8; ++i) s += sred[i];
            atomicAdd(sse_acc, s);
        }
    }
}

__global__ __launch_bounds__(512) void vq_final_a(const float* __restrict__ counts,
                                                  const double* __restrict__ sse_acc,
                                                  float* __restrict__ out) {
    __shared__ double red[512];
    const int k = threadIdx.x;
    const double p = (double)counts[k] / (double)NTOK;
    red[k] = p * log(p + 1e-10);
    __syncthreads();
#pragma unroll
    for (int st = 256; st > 0; st >>= 1) {
        if (k < st) red[k] += red[k + st];
        __syncthreads();
    }
    if (k == 0) {
        out[NELEM] = (float)((*sse_acc / (double)NELEM) * 1.25);
        out[NELEM + 1] = (float)exp(-red[0]);
    }
}

extern "C" void kernel_launch(void* const* d_in, const int* in_sizes, int n_in,
                              void* d_out, int out_size, void* d_ws, size_t ws_size,
                              hipStream_t stream) {
    const float* in = (const float*)d_in[0];
    const float* w = (const float*)d_in[1];
    float* out = (float*)d_out;
    char* ws = (char*)d_ws;

    const size_t PC = 0;                          // 1 MB u32 partials
    const size_t SS = (size_t)512 * 512 * 4;      // +4 KB ssep u64[512]
    const size_t FL = SS + 512 * 8;               // +2 KB flags u32[512]
    const size_t need = FL + 512 * 4;
    if (ws_size >= need) {
        unsigned* pcounts = (unsigned*)(ws + PC);
        unsigned long long* ssep = (unsigned long long*)(ws + SS);
        unsigned* flags = (unsigned*)(ws + FL);
        vq_main<<<512, 512, 0, stream>>>(in, w, out, pcounts, ssep, flags,
                                         nullptr, nullptr, 0);
    } else {  // fallback: R6-style atomics
        float* counts = (float*)ws;
        double* sse_acc = (double*)(ws + 2048);
        (void)hipMemsetAsync(ws, 0, 2056, stream);
        vq_main<<<512, 512, 0, stream>>>(in, w, out, nullptr, nullptr, nullptr,
                                         counts, sse_acc, 1);
        vq_final_a<<<1, 512, 0, stream>>>(counts, sse_acc, out);
    }
}

// Round 9
// 116.226 us; speedup vs baseline: 1.1832x; 1.1832x over previous
//
#include <hip/hip_runtime.h>
#include <math.h>

// VectorQuantizer on MI355X — R19: decompose vq_main for attribution.
// R18 post-mortem: agent-RELEASE flag = buffer_wbl2 per block = the SAME
// ~40 µs XCD-L2 drain as R12/R13's threadfence. Fusion is dead (3 strikes).
// Open problem: vq_main ~40 µs across 3 structures (R10/R14/R17) with all
// pipes idle and invisible under the 43.5 µs fill cutoff -> split it:
//  A) vq_scan: X gather + split-K MFMA argmin; writes idx u16[131072],
//     pcounts u16, ssep. No out-stream in its critical path.
//  B) vq_copy: pure stream gather-copy, 1 float4/thread, fully coalesced
//     (w rows L2-hot + idx broadcast -> out). Fill-like regime, ~6-9 µs.
// Bit-identical: same keys/sse/out values. Each part now profiler-visible.
// Lessons kept: no nontemporal (R12), no cross-block fences/releases
// (R12/R13/R18), plain cached stores, two(-plus-one)-kernel graph.
// ws: [0,512K) pcounts u16[512][512] | +4K ssep f64[512] | +256K idx u16

#define NTOK 131072
#define KCODES 512
#define HW 4096
#define CHW 262144
#define NELEM 8388608

typedef __attribute__((ext_vector_type(8))) short short8;
typedef __attribute__((ext_vector_type(4))) float f32x4;
typedef __attribute__((ext_vector_type(4))) unsigned short u16x4;

static __device__ __forceinline__ unsigned short f2bf(float f) {
    unsigned u = __float_as_uint(f);
    unsigned r = u + 0x7FFFu + ((u >> 16) & 1u);  // RNE
    return (unsigned short)(r >> 16);
}

__global__ __launch_bounds__(512, 8) void vq_scan(const float* __restrict__ in,
                                                  const float* __restrict__ w,
                                                  float* __restrict__ out,
                                                  unsigned short* __restrict__ idx16,
                                                  unsigned short* __restrict__ pcounts,
                                                  double* __restrict__ ssep,
                                                  float* __restrict__ counts,
                                                  double* __restrict__ sse_acc,
                                                  const int amode) {
    __shared__ __align__(16) unsigned short wh[256 * 64];  // 32768 B half-codebook
    __shared__ float wsqp[KCODES];              // 2048 B: 1.25 + ||w_k||^2
    __shared__ int idxbuf[256];                 // 1024 B
    __shared__ int hist[KCODES];                // 2048 B block histogram
    __shared__ double sred[8];                  // per-wave sse partials

    const int tid = threadIdx.x;
    const int lane = tid & 63, wv = tid >> 6;   // wv in [0,8)
    const int col = lane & 15, quad = lane >> 4;
    const int ntok0 = blockIdx.x * 256;         // 512 blocks x 256 tokens

    wsqp[tid] = 1.25f;
    hist[tid] = 0;
    __syncthreads();  // B1

    // ---- pass-0 W staging (codes 0..255) interleaved with all X loads ----
    const float* gbase = in + (ntok0 >> 12) * CHW + (ntok0 & 4095) + wv * 32 + col;
    short8 ah[2][2];
    float xsq = 0.f;
#pragma unroll
    for (int it = 0; it < 8; ++it) {
        const int sub = it >> 2, c = (it >> 1) & 1, j0 = (it & 1) * 4;
        const float* gp = gbase + sub * 16 + (c * 32 + quad * 8 + j0) * HW;
        const float x0 = gp[0 * HW], x1 = gp[1 * HW], x2 = gp[2 * HW], x3 = gp[3 * HW];

        if (it < 4) {
            const int g = it * 512 + tid;  // [0,2048): 256 codes x 8 chunks
            const int cc = g & 15, qd = (g >> 4) & 3, ch = (g >> 6) & 1, tt = g >> 7;
            const int code = tt * 16 + cc;
            const float4* src = (const float4*)(w + code * 64 + ch * 32 + qd * 8);
            const float4 v0 = src[0], v1 = src[1];
            short8 hv;
            hv[0] = (short)f2bf(v0.x); hv[1] = (short)f2bf(v0.y);
            hv[2] = (short)f2bf(v0.z); hv[3] = (short)f2bf(v0.w);
            hv[4] = (short)f2bf(v1.x); hv[5] = (short)f2bf(v1.y);
            hv[6] = (short)f2bf(v1.z); hv[7] = (short)f2bf(v1.w);
            *(short8*)(wh + g * 8) = hv;
            float ws2 = v0.x * v0.x;
            ws2 = fmaf(v0.y, v0.y, ws2); ws2 = fmaf(v0.z, v0.z, ws2);
            ws2 = fmaf(v0.w, v0.w, ws2); ws2 = fmaf(v1.x, v1.x, ws2);
            ws2 = fmaf(v1.y, v1.y, ws2); ws2 = fmaf(v1.z, v1.z, ws2);
            ws2 = fmaf(v1.w, v1.w, ws2);
            atomicAdd(&wsqp[code], ws2);  // LDS atomic
        }

        ah[sub][c][j0 + 0] = (short)f2bf(-2.0f * x0);
        ah[sub][c][j0 + 1] = (short)f2bf(-2.0f * x1);
        ah[sub][c][j0 + 2] = (short)f2bf(-2.0f * x2);
        ah[sub][c][j0 + 3] = (short)f2bf(-2.0f * x3);
        xsq = fmaf(x0, x0, xsq); xsq = fmaf(x1, x1, xsq);
        xsq = fmaf(x2, x2, xsq); xsq = fmaf(x3, x3, xsq);
    }
    __syncthreads();  // B2: pass-0 wh + wsqp[0:256]

    unsigned runkey[2][4];
#pragma unroll
    for (int sub = 0; sub < 2; ++sub)
#pragma unroll
        for (int r = 0; r < 4; ++r) runkey[sub][r] = 0xFFFFFFFFu;

    // ---- scan pass 0: codes 0..255 ----
#pragma unroll 1
    for (int t = 0; t < 16; ++t) {
        const unsigned short* ph = wh + t * 1024 + quad * 128 + col * 8;
        const short8 b0 = *(const short8*)ph;
        const short8 b1 = *(const short8*)(ph + 512);
        const int code = t * 16 + col;
        const float seed = wsqp[code];
#pragma unroll
        for (int sub = 0; sub < 2; ++sub) {
            f32x4 acc = {seed, seed, seed, seed};
            acc = __builtin_amdgcn_mfma_f32_16x16x32_bf16(ah[sub][0], b0, acc, 0, 0, 0);
            acc = __builtin_amdgcn_mfma_f32_16x16x32_bf16(ah[sub][1], b1, acc, 0, 0, 0);
#pragma unroll
            for (int r = 0; r < 4; ++r) {
                const unsigned key = (__float_as_uint(acc[r]) << 9) | code;
                runkey[sub][r] = key < runkey[sub][r] ? key : runkey[sub][r];
            }
        }
    }
    __syncthreads();  // B3: done reading pass-0 wh

    // ---- pass-1 staging (codes 256..511) ----
#pragma unroll
    for (int it = 0; it < 4; ++it) {
        const int g = it * 512 + tid;
        const int cc = g & 15, qd = (g >> 4) & 3, ch = (g >> 6) & 1, tt = g >> 7;
        const int code = 256 + tt * 16 + cc;
        const float4* src = (const float4*)(w + code * 64 + ch * 32 + qd * 8);
        const float4 v0 = src[0], v1 = src[1];
        short8 hv;
        hv[0] = (short)f2bf(v0.x); hv[1] = (short)f2bf(v0.y);
        hv[2] = (short)f2bf(v0.z); hv[3] = (short)f2bf(v0.w);
        hv[4] = (short)f2bf(v1.x); hv[5] = (short)f2bf(v1.y);
        hv[6] = (short)f2bf(v1.z); hv[7] = (short)f2bf(v1.w);
        *(short8*)(wh + g * 8) = hv;
        float ws2 = v0.x * v0.x;
        ws2 = fmaf(v0.y, v0.y, ws2); ws2 = fmaf(v0.z, v0.z, ws2);
        ws2 = fmaf(v0.w, v0.w, ws2); ws2 = fmaf(v1.x, v1.x, ws2);
        ws2 = fmaf(v1.y, v1.y, ws2); ws2 = fmaf(v1.z, v1.z, ws2);
        ws2 = fmaf(v1.w, v1.w, ws2);
        atomicAdd(&wsqp[code], ws2);
    }
    __syncthreads();  // B4: pass-1 wh + wsqp[256:512]

    // ---- scan pass 1: codes 256..511 ----
#pragma unroll 1
    for (int t = 0; t < 16; ++t) {
        const unsigned short* ph = wh + t * 1024 + quad * 128 + col * 8;
        const short8 b0 = *(const short8*)ph;
        const short8 b1 = *(const short8*)(ph + 512);
        const int code = 256 + t * 16 + col;
        const float seed = wsqp[code];
#pragma unroll
        for (int sub = 0; sub < 2; ++sub) {
            f32x4 acc = {seed, seed, seed, seed};
            acc = __builtin_amdgcn_mfma_f32_16x16x32_bf16(ah[sub][0], b0, acc, 0, 0, 0);
            acc = __builtin_amdgcn_mfma_f32_16x16x32_bf16(ah[sub][1], b1, acc, 0, 0, 0);
#pragma unroll
            for (int r = 0; r < 4; ++r) {
                const unsigned key = (__float_as_uint(acc[r]) << 9) | code;
                runkey[sub][r] = key < runkey[sub][r] ? key : runkey[sub][r];
            }
        }
    }

    // ---- cross-lane argmin over the 16 code-cols ----
#pragma unroll
    for (int s = 1; s < 16; s <<= 1)
#pragma unroll
        for (int sub = 0; sub < 2; ++sub)
#pragma unroll
            for (int r = 0; r < 4; ++r) {
                const unsigned o = __shfl_xor(runkey[sub][r], s, 64);
                runkey[sub][r] = o < runkey[sub][r] ? o : runkey[sub][r];
            }

    // d_best (exact from key) + publish indices (wave-local consumers)
    float dsum = 0.f;
    if (col == 0) {
#pragma unroll
        for (int sub = 0; sub < 2; ++sub)
#pragma unroll
            for (int r = 0; r < 4; ++r) {
                const unsigned key = runkey[sub][r];
                idxbuf[wv * 32 + sub * 16 + quad * 4 + r] = (int)(key & 511u);
                dsum += __uint_as_float((key >> 9) | 0x3F800000u) - 1.25f;
            }
    }
    float contrib = xsq + dsum;
#pragma unroll
    for (int off = 32; off > 0; off >>= 1) contrib += __shfl_down(contrib, off, 64);
    if (lane == 0) sred[wv] = (double)contrib;

    // per-wave histogram over wave-local idxbuf (no barrier needed)
    if (lane < 32) atomicAdd(&hist[idxbuf[wv * 32 + lane]], 1);
    __syncthreads();  // B5: idxbuf + hist + sred complete

    if (!amode) {
        if (tid < 256) idx16[ntok0 + tid] = (unsigned short)idxbuf[tid];
        pcounts[(blockIdx.x << 9) + tid] = (unsigned short)hist[tid];
        if (tid == 0) {
            double s = sred[0];
#pragma unroll
            for (int i = 1; i < 8; ++i) s += sred[i];
            ssep[blockIdx.x] = s;
        }
    } else {  // fallback: no ws for idx/partials -> do epilogue inline (R17)
#pragma unroll
        for (int p = 0; p < 2; ++p) {
            const int tl = p * 16 + (lane >> 2), q = lane & 3;
            const int n = ntok0 + wv * 32 + tl;
            const int bidx = idxbuf[wv * 32 + tl];
            const float4* wr = (const float4*)(w + bidx * 64 + q * 16);
            float4* op = (float4*)(out + n * 64 + q * 16);
#pragma unroll
            for (int i = 0; i < 4; ++i) op[i] = wr[i];
        }
        const int h = hist[tid];
        if (h) atomicAdd(&counts[tid], (float)h);
        if (tid == 0) {
            double s = sred[0];
#pragma unroll
            for (int i = 1; i < 8; ++i) s += sred[i];
            atomicAdd(sse_acc, s);
        }
    }
}

// pure streaming gather-copy: thread g -> one float4. n = g>>4, sub = g&15.
// idx broadcast (16 lanes share), w rows L2-hot, out fully coalesced.
__global__ __launch_bounds__(256) void vq_copy(const float* __restrict__ w,
                                               const unsigned short* __restrict__ idx16,
                                               float* __restrict__ out) {
    const int g = blockIdx.x * 256 + threadIdx.x;   // 8192 blocks x 256
    const int n = g >> 4, sub = g & 15;
    const int bidx = (int)idx16[n];
    const float4 v = *(const float4*)(w + bidx * 64 + sub * 4);
    *(float4*)(out + n * 64 + sub * 4) = v;
}

// parallel reduce: thread t owns 4 codes x 1 block-quarter; u16x4 coalesced
__global__ __launch_bounds__(512) void vq_final_p(const unsigned short* __restrict__ pcounts,
                                                  const double* __restrict__ ssep,
                                                  float* __restrict__ out) {
    __shared__ float part[4][512];   // 8 KB: quarter x code
    __shared__ double red[512];
    __shared__ double sred[512];
    const int t = threadIdx.x;
    const int q = t >> 7, c4 = (t & 127) << 2;

    const u16x4* base = (const u16x4*)pcounts + (q << 14) + (c4 >> 2);
    float4 s = {0.f, 0.f, 0.f, 0.f};
#pragma unroll 16
    for (int b = 0; b < 128; ++b) {        // rows q*128 .. q*128+128
        const u16x4 v = base[b << 7];      // stride 512 ushorts = 128 u16x4
        s.x += (float)v[0]; s.y += (float)v[1];
        s.z += (float)v[2]; s.w += (float)v[3];
    }
    *(float4*)&part[q][c4] = s;
    sred[t] = ssep[t];
    __syncthreads();

    const float cnt = part[0][t] + part[1][t] + part[2][t] + part[3][t];
    const double p = (double)cnt / (double)NTOK;
    red[t] = p * log(p + 1e-10);
    __syncthreads();
#pragma unroll
    for (int st = 256; st > 0; st >>= 1) {
        if (t < st) { red[t] += red[t + st]; sred[t] += sred[t + st]; }
        __syncthreads();
    }
    if (t == 0) {
        out[NELEM] = (float)((sred[0] / (double)NELEM) * 1.25);
        out[NELEM + 1] = (float)exp(-red[0]);
    }
}

__global__ __launch_bounds__(512) void vq_final_a(const float* __restrict__ counts,
                                                  const double* __restrict__ sse_acc,
                                                  float* __restrict__ out) {
    __shared__ double red[512];
    const int k = threadIdx.x;
    const double p = (double)counts[k] / (double)NTOK;
    red[k] = p * log(p + 1e-10);
    __syncthreads();
#pragma unroll
    for (int st = 256; st > 0; st >>= 1) {
        if (k < st) red[k] += red[k + st];
        __syncthreads();
    }
    if (k == 0) {
        out[NELEM] = (float)((*sse_acc / (double)NELEM) * 1.25);
        out[NELEM + 1] = (float)exp(-red[0]);
    }
}

extern "C" void kernel_launch(void* const* d_in, const int* in_sizes, int n_in,
                              void* d_out, int out_size, void* d_ws, size_t ws_size,
                              hipStream_t stream) {
    const float* in = (const float*)d_in[0];
    const float* w = (const float*)d_in[1];
    float* out = (float*)d_out;
    char* ws = (char*)d_ws;

    const size_t PC = 0;                          // 512 KB u16 partials
    const size_t SS = (size_t)512 * 512 * 2;      // +4 KB ssep f64[512]
    const size_t IX = SS + 512 * 8;               // +256 KB idx u16[131072]
    const size_t need = IX + (size_t)NTOK * 2;
    if (ws_size >= need) {
        unsigned short* pcounts = (unsigned short*)(ws + PC);
        double* ssep = (double*)(ws + SS);
        unsigned short* idx16 = (unsigned short*)(ws + IX);
        vq_scan<<<512, 512, 0, stream>>>(in, w, out, idx16, pcounts, ssep,
                                         nullptr, nullptr, 0);
        vq_copy<<<8192, 256, 0, stream>>>(w, idx16, out);
        vq_final_p<<<1, 512, 0, stream>>>(pcounts, ssep, out);
    } else {  // fallback: R17-style inline epilogue + atomics
        float* counts = (float*)ws;
        double* sse_acc = (double*)(ws + 2048);
        (void)hipMemsetAsync(ws, 0, 2056, stream);
        vq_scan<<<512, 512, 0, stream>>>(in, w, out, nullptr, nullptr, nullptr,
                                         counts, sse_acc, 1);
        vq_final_a<<<1, 512, 0, stream>>>(counts, sse_acc, out);
    }
}

// Round 10
// 115.696 us; speedup vs baseline: 1.1886x; 1.0046x over previous
//
#include <hip/hip_runtime.h>
#include <math.h>

// VectorQuantizer on MI355X — R20: hoist W-staging out of the block loop.
// Scan body stuck at ~40 µs across R10/R14/R17/R19 with all pipes idle and
// occupancy proven non-binding (R16/R17). Remaining per-block serializer:
// 64 KB f2bf staging VALU + LDS-atomic wsq + 3 full-block barriers before
// MFMA can issue — repeated by all 512 blocks for IDENTICAL data.
// R20: vq_pack (1 block, once) pre-packs bf16 codebook in MFMA B-fragment
// order (64 KB) + 1.25+||w||^2 seeds (2 KB) into ws. vq_scan reads fragments
// straight from global: per tile 2x1KB contiguous L2-hot wave-loads (16 MB
// L2 traffic total ~0.5 µs). No wh LDS (5.5 KB total), no f2bf in hot path,
// barriers 5 -> 2. unroll 4 + launch_bounds(512,4) for load pipelining.
// wsq now fixed-order (was LDS-atomic nondeterministic anyway; ~1ulp).
// Lessons kept: no nontemporal (R12), no cross-block fences (R12/R13/R18),
// plain cached epilogue, separate final_p kernel (fusion dead, 3 strikes).
// ws: [0,64K) wpack u16 | [64K,66K) wsqf f32[512]
//     | [66K,+512K) pcounts u16[512][512] | +4K ssep f64[512]

#define NTOK 131072
#define KCODES 512
#define HW 4096
#define CHW 262144
#define NELEM 8388608

typedef __attribute__((ext_vector_type(8))) short short8;
typedef __attribute__((ext_vector_type(4))) float f32x4;
typedef __attribute__((ext_vector_type(4))) unsigned short u16x4;

static __device__ __forceinline__ unsigned short f2bf(float f) {
    unsigned u = __float_as_uint(f);
    unsigned r = u + 0x7FFFu + ((u >> 16) & 1u);  // RNE
    return (unsigned short)(r >> 16);
}

// one-shot: pack codebook into MFMA B-fragment order + compute seeds.
// layout: chunk g = tt*128 + ch*64 + qd*16 + cc  (code = tt*16+cc) holds
// bf16 of w[code*64 + ch*32 + qd*8 + 0..7] at wpack[g*8..g*8+7].
__global__ __launch_bounds__(512) void vq_pack(const float* __restrict__ w,
                                               unsigned short* __restrict__ wpack,
                                               float* __restrict__ wsqf) {
    const int code = threadIdx.x;               // 512 threads, 1 block
    const int tt = code >> 4, cc = code & 15;
    const float4* src = (const float4*)(w + code * 64);
    float4 v[16];
#pragma unroll
    for (int i = 0; i < 16; ++i) v[i] = src[i];
    float s = 0.f;
#pragma unroll
    for (int i = 0; i < 16; ++i) {
        s = fmaf(v[i].x, v[i].x, s); s = fmaf(v[i].y, v[i].y, s);
        s = fmaf(v[i].z, v[i].z, s); s = fmaf(v[i].w, v[i].w, s);
    }
    wsqf[code] = 1.25f + s;
#pragma unroll
    for (int ch = 0; ch < 2; ++ch)
#pragma unroll
        for (int qd = 0; qd < 4; ++qd) {
            const int g = tt * 128 + ch * 64 + qd * 16 + cc;
            const int e0 = ch * 8 + qd * 2;     // float4 index of elem ch*32+qd*8
            const float4 a = v[e0], b = v[e0 + 1];
            short8 hv;
            hv[0] = (short)f2bf(a.x); hv[1] = (short)f2bf(a.y);
            hv[2] = (short)f2bf(a.z); hv[3] = (short)f2bf(a.w);
            hv[4] = (short)f2bf(b.x); hv[5] = (short)f2bf(b.y);
            hv[6] = (short)f2bf(b.z); hv[7] = (short)f2bf(b.w);
            *(short8*)(wpack + g * 8) = hv;
        }
}

__global__ __launch_bounds__(512, 4) void vq_scan(const float* __restrict__ in,
                                                  const float* __restrict__ w,
                                                  const unsigned short* __restrict__ wpack,
                                                  const float* __restrict__ wsqf,
                                                  float* __restrict__ out,
                                                  unsigned short* __restrict__ pcounts,
                                                  double* __restrict__ ssep,
                                                  float* __restrict__ counts,
                                                  double* __restrict__ sse_acc,
                                                  const int amode) {
    __shared__ float wsqp[KCODES];              // 2048 B seeds
    __shared__ int idxbuf[256];                 // 1024 B
    __shared__ int hist[KCODES];                // 2048 B
    __shared__ double sred[8];

    const int tid = threadIdx.x;
    const int lane = tid & 63, wv = tid >> 6;   // wv in [0,8)
    const int col = lane & 15, quad = lane >> 4;
    const int ntok0 = blockIdx.x * 256;         // 512 blocks x 256 tokens

    wsqp[tid] = wsqf[tid];
    hist[tid] = 0;
    __syncthreads();  // B1: seeds + hist ready

    // ---- X gather + ah pack (register-local; no barrier after) ----
    const float* gbase = in + (ntok0 >> 12) * CHW + (ntok0 & 4095) + wv * 32 + col;
    short8 ah[2][2];
    float xsq = 0.f;
#pragma unroll
    for (int it = 0; it < 8; ++it) {
        const int sub = it >> 2, c = (it >> 1) & 1, j0 = (it & 1) * 4;
        const float* gp = gbase + sub * 16 + (c * 32 + quad * 8 + j0) * HW;
        const float x0 = gp[0 * HW], x1 = gp[1 * HW], x2 = gp[2 * HW], x3 = gp[3 * HW];
        ah[sub][c][j0 + 0] = (short)f2bf(-2.0f * x0);
        ah[sub][c][j0 + 1] = (short)f2bf(-2.0f * x1);
        ah[sub][c][j0 + 2] = (short)f2bf(-2.0f * x2);
        ah[sub][c][j0 + 3] = (short)f2bf(-2.0f * x3);
        xsq = fmaf(x0, x0, xsq); xsq = fmaf(x1, x1, xsq);
        xsq = fmaf(x2, x2, xsq); xsq = fmaf(x3, x3, xsq);
    }

    // ---- scan 32 tiles; B-fragments straight from global (L2-hot) ----
    const unsigned short* pb = wpack + quad * 128 + col * 8;
    unsigned runkey[2][4];
#pragma unroll
    for (int sub = 0; sub < 2; ++sub)
#pragma unroll
        for (int r = 0; r < 4; ++r) runkey[sub][r] = 0xFFFFFFFFu;

#pragma unroll 4
    for (int t = 0; t < 32; ++t) {
        const short8 b0 = *(const short8*)(pb + t * 1024);
        const short8 b1 = *(const short8*)(pb + t * 1024 + 512);
        const int code = t * 16 + col;
        const float seed = wsqp[code];
#pragma unroll
        for (int sub = 0; sub < 2; ++sub) {
            f32x4 acc = {seed, seed, seed, seed};
            acc = __builtin_amdgcn_mfma_f32_16x16x32_bf16(ah[sub][0], b0, acc, 0, 0, 0);
            acc = __builtin_amdgcn_mfma_f32_16x16x32_bf16(ah[sub][1], b1, acc, 0, 0, 0);
#pragma unroll
            for (int r = 0; r < 4; ++r) {
                const unsigned key = (__float_as_uint(acc[r]) << 9) | code;
                runkey[sub][r] = key < runkey[sub][r] ? key : runkey[sub][r];
            }
        }
    }

    // ---- cross-lane argmin over the 16 code-cols ----
#pragma unroll
    for (int s = 1; s < 16; s <<= 1)
#pragma unroll
        for (int sub = 0; sub < 2; ++sub)
#pragma unroll
            for (int r = 0; r < 4; ++r) {
                const unsigned o = __shfl_xor(runkey[sub][r], s, 64);
                runkey[sub][r] = o < runkey[sub][r] ? o : runkey[sub][r];
            }

    // d_best (exact from key) + publish indices (wave-local consumers)
    float dsum = 0.f;
    if (col == 0) {
#pragma unroll
        for (int sub = 0; sub < 2; ++sub)
#pragma unroll
            for (int r = 0; r < 4; ++r) {
                const unsigned key = runkey[sub][r];
                idxbuf[wv * 32 + sub * 16 + quad * 4 + r] = (int)(key & 511u);
                dsum += __uint_as_float((key >> 9) | 0x3F800000u) - 1.25f;
            }
    }
    float contrib = xsq + dsum;
#pragma unroll
    for (int off = 32; off > 0; off >>= 1) contrib += __shfl_down(contrib, off, 64);
    if (lane == 0) sred[wv] = (double)contrib;

    // per-wave histogram over wave-local idxbuf (no barrier needed)
    if (lane < 32) atomicAdd(&hist[idxbuf[wv * 32 + lane]], 1);

    // ---- epilogue: out = w rows (L2-hot); 4 lanes/token, 2 passes ----
#pragma unroll
    for (int p = 0; p < 2; ++p) {
        const int tl = p * 16 + (lane >> 2), q = lane & 3;
        const int n = ntok0 + wv * 32 + tl;
        const int bidx = idxbuf[wv * 32 + tl];
        const float4* wr = (const float4*)(w + bidx * 64 + q * 16);
        float4* op = (float4*)(out + n * 64 + q * 16);
#pragma unroll
        for (int i = 0; i < 4; ++i) op[i] = wr[i];
    }
    __syncthreads();  // B2: hist + sred complete

    if (!amode) {
        pcounts[(blockIdx.x << 9) + tid] = (unsigned short)hist[tid];
        if (tid == 0) {
            double s = sred[0];
#pragma unroll
            for (int i = 1; i < 8; ++i) s += sred[i];
            ssep[blockIdx.x] = s;
        }
    } else {  // fallback: atomics into tiny ws
        const int h = hist[tid];
        if (h) atomicAdd(&counts[tid], (float)h);
        if (tid == 0) {
            double s = sred[0];
#pragma unroll
            for (int i = 1; i < 8; ++i) s += sred[i];
            atomicAdd(sse_acc, s);
        }
    }
}

// parallel reduce: thread t owns 4 codes x 1 block-quarter; u16x4 coalesced
__global__ __launch_bounds__(512) void vq_final_p(const unsigned short* __restrict__ pcounts,
                                                  const double* __restrict__ ssep,
                                                  float* __restrict__ out) {
    __shared__ float part[4][512];   // 8 KB: quarter x code
    __shared__ double red[512];
    __shared__ double sred[512];
    const int t = threadIdx.x;
    const int q = t >> 7, c4 = (t & 127) << 2;

    const u16x4* base = (const u16x4*)pcounts + (q << 14) + (c4 >> 2);
    float4 s = {0.f, 0.f, 0.f, 0.f};
#pragma unroll 16
    for (int b = 0; b < 128; ++b) {        // rows q*128 .. q*128+128
        const u16x4 v = base[b << 7];      // stride 512 ushorts = 128 u16x4
        s.x += (float)v[0]; s.y += (float)v[1];
        s.z += (float)v[2]; s.w += (float)v[3];
    }
    *(float4*)&part[q][c4] = s;
    sred[t] = ssep[t];
    __syncthreads();

    const float cnt = part[0][t] + part[1][t] + part[2][t] + part[3][t];
    const double p = (double)cnt / (double)NTOK;
    red[t] = p * log(p + 1e-10);
    __syncthreads();
#pragma unroll
    for (int st = 256; st > 0; st >>= 1) {
        if (t < st) { red[t] += red[t + st]; sred[t] += sred[t + st]; }
        __syncthreads();
    }
    if (t == 0) {
        out[NELEM] = (float)((sred[0] / (double)NELEM) * 1.25);
        out[NELEM + 1] = (float)exp(-red[0]);
    }
}

__global__ __launch_bounds__(512) void vq_final_a(const float* __restrict__ counts,
                                                  const double* __restrict__ sse_acc,
                                                  float* __restrict__ out) {
    __shared__ double red[512];
    const int k = threadIdx.x;
    const double p = (double)counts[k] / (double)NTOK;
    red[k] = p * log(p + 1e-10);
    __syncthreads();
#pragma unroll
    for (int st = 256; st > 0; st >>= 1) {
        if (k < st) red[k] += red[k + st];
        __syncthreads();
    }
    if (k == 0) {
        out[NELEM] = (float)((*sse_acc / (double)NELEM) * 1.25);
        out[NELEM + 1] = (float)exp(-red[0]);
    }
}

extern "C" void kernel_launch(void* const* d_in, const int* in_sizes, int n_in,
                              void* d_out, int out_size, void* d_ws, size_t ws_size,
                              hipStream_t stream) {
    const float* in = (const float*)d_in[0];
    const float* w = (const float*)d_in[1];
    float* out = (float*)d_out;
    char* ws = (char*)d_ws;

    const size_t WP = 0;                          // 64 KB wpack
    const size_t WQ = 65536;                      // +2 KB wsqf
    const size_t PC = WQ + 2048;                  // +512 KB pcounts u16
    const size_t SSo = PC + (size_t)512 * 512 * 2;  // +4 KB ssep
    const size_t need_full = SSo + 512 * 8;
    const size_t need_min = PC + 2048 + 8;        // counts + sse_acc

    unsigned short* wpack = (unsigned short*)(ws + WP);
    float* wsqf = (float*)(ws + WQ);

    if (ws_size >= need_full) {
        unsigned short* pcounts = (unsigned short*)(ws + PC);
        double* ssep = (double*)(ws + SSo);
        vq_pack<<<1, 512, 0, stream>>>(w, wpack, wsqf);
        vq_scan<<<512, 512, 0, stream>>>(in, w, wpack, wsqf, out, pcounts, ssep,
                                         nullptr, nullptr, 0);
        vq_final_p<<<1, 512, 0, stream>>>(pcounts, ssep, out);
    } else if (ws_size >= need_min) {  // fallback: atomic finals
        float* counts = (float*)(ws + PC);
        double* sse_acc = (double*)(ws + PC + 2048);
        (void)hipMemsetAsync(ws + PC, 0, 2056, stream);
        vq_pack<<<1, 512, 0, stream>>>(w, wpack, wsqf);
        vq_scan<<<512, 512, 0, stream>>>(in, w, wpack, wsqf, out, nullptr, nullptr,
                                         counts, sse_acc, 1);
        vq_final_a<<<1, 512, 0, stream>>>(counts, sse_acc, out);
    }
}